// Round 10
// baseline (50.274 us; speedup 1.0000x reference)
//
#include <hip/hip_runtime.h>
#include <math.h>

// out[n] = sum_k exp2( t[n,k] ),  t[n,k] = sum_{j<10} P[n,j]*G[k,j]
// P = (x0^2,x1^2,x2^2, x0x1,x0x2,x1x2, x0,x1,x2, 1)
// G = h*(A00,A11,A22), 2h*(A01,A02,A12), L2E*(b0,b1,b2), h*c + log2(amp), h=-0.5*log2(e)
//
// MFMA f16 split-2 trick (one mfma_f32_16x16x32_f16 per 16x16 tile):
//   A cols [0..31] = [Phi(10) | Phi(10) | Plo(10) | 0 0]
//   B rows [0..31] = [Ghi(10) | Glo(10) | Ghi(10) | 0 0]
//
// exp2 via mean-zero Schraudolph:
//   y4 = pk_fma(c4, 2^23, B) (2x v_pk_fma_f32); u = v_cvt_u32_f32(y) per lane
//   (HW-saturating: y<0 -> 0, so t<=-126 incl. -60000 pad -> exactly 0);
//   acc.comp += bitcast<float>(u) as 4 scalar v_add_f32 (no adjacency needed).
// MFMA C operand = pinned zero quad (materialized once, never re-zeroed).

typedef _Float16 half8 __attribute__((ext_vector_type(8)));
typedef float    f32x4 __attribute__((ext_vector_type(4)));

#define PT     4    // point-tiles (16 points) per wave
#define WPB    4    // waves per block
#define KSPLIT 8    // gaussian-tile splits (blockIdx.y)

#define EXP_SCALE 8388608.0f        // 2^23
#define EXP_BIAS  1064880938.0f     // (127 - 0.0563) * 2^23, mean-zero bias

__device__ __forceinline__ unsigned cvt_u32_sat(float y) {
    unsigned u;
    asm("v_cvt_u32_f32 %0, %1" : "=v"(u) : "v"(y));   // saturates: y<0 -> 0
    return u;
}

__global__ __launch_bounds__(256) void gmf_precompute(
        const float* __restrict__ means,
        const float* __restrict__ log_scales,
        const float* __restrict__ quats,
        const float* __restrict__ log_amps,
        _Float16* __restrict__ Bf, int K, int KT) {
    int k = blockIdx.x * blockDim.x + threadIdx.x;
    if (k >= KT * 16) return;

    float gc[10];
    if (k < K) {
        float qw = quats[4*k+0], qx = quats[4*k+1], qy = quats[4*k+2], qz = quats[4*k+3];
        float qn = rsqrtf(qw*qw + qx*qx + qy*qy + qz*qz);
        qw *= qn; qx *= qn; qy *= qn; qz *= qn;

        float r00 = 1.f - 2.f*(qy*qy + qz*qz);
        float r01 = 2.f*(qx*qy - qw*qz);
        float r02 = 2.f*(qx*qz + qw*qy);
        float r10 = 2.f*(qx*qy + qw*qz);
        float r11 = 1.f - 2.f*(qx*qx + qz*qz);
        float r12 = 2.f*(qy*qz - qw*qx);
        float r20 = 2.f*(qx*qz - qw*qy);
        float r21 = 2.f*(qy*qz + qw*qx);
        float r22 = 1.f - 2.f*(qx*qx + qy*qy);

        float s0 = fminf(fmaxf(expf(log_scales[3*k+0]), 1e-5f), 100.f);
        float s1 = fminf(fmaxf(expf(log_scales[3*k+1]), 1e-5f), 100.f);
        float s2 = fminf(fmaxf(expf(log_scales[3*k+2]), 1e-5f), 100.f);
        float v0 = s0*s0, v1 = s1*s1, v2 = s2*s2;

        float S00 = r00*r00*v0 + r01*r01*v1 + r02*r02*v2 + 1e-5f;
        float S11 = r10*r10*v0 + r11*r11*v1 + r12*r12*v2 + 1e-5f;
        float S22 = r20*r20*v0 + r21*r21*v1 + r22*r22*v2 + 1e-5f;
        float S01 = r00*r10*v0 + r01*r11*v1 + r02*r12*v2;
        float S02 = r00*r20*v0 + r01*r21*v1 + r02*r22*v2;
        float S12 = r10*r20*v0 + r11*r21*v1 + r12*r22*v2;

        float c00 = S11*S22 - S12*S12;
        float c01 = S02*S12 - S01*S22;
        float c02 = S01*S12 - S02*S11;
        float det = S00*c00 + S01*c01 + S02*c02;
        float id  = 1.f/det;
        float A00 = c00*id, A01 = c01*id, A02 = c02*id;
        float A11 = (S00*S22 - S02*S02)*id;
        float A12 = (S01*S02 - S00*S12)*id;
        float A22 = (S00*S11 - S01*S01)*id;

        float m0 = means[3*k+0], m1 = means[3*k+1], m2 = means[3*k+2];
        float b0 = A00*m0 + A01*m1 + A02*m2;
        float b1 = A01*m0 + A11*m1 + A12*m2;
        float b2 = A02*m0 + A12*m1 + A22*m2;
        float cc = b0*m0 + b1*m1 + b2*m2;

        float la = fminf(fmaxf(log_amps[k], -10.f), 6.f);
        const float L2E = 1.4426950408889634f;
        const float h = -0.5f * L2E;

        gc[0] = h*A00; gc[1] = h*A11; gc[2] = h*A22;
        gc[3] = 2.f*h*A01; gc[4] = 2.f*h*A02; gc[5] = 2.f*h*A12;
        gc[6] = L2E*b0; gc[7] = L2E*b1; gc[8] = L2E*b2;
        gc[9] = h*cc + L2E*la;
    } else {
        #pragma unroll
        for (int j = 0; j < 10; ++j) gc[j] = 0.f;
        gc[9] = -60000.f;   // pad gaussian -> saturates to 0 in fast exp2
    }

    _Float16 gh[10], gl[10];
    #pragma unroll
    for (int j = 0; j < 10; ++j) {
        gh[j] = (_Float16)gc[j];
        gl[j] = (_Float16)(gc[j] - (float)gh[j]);
    }

    int kt = k >> 4, c = k & 15;
    _Float16* dst = Bf + (size_t)kt * 64 * 8;
    #pragma unroll 32
    for (int r = 0; r < 32; ++r) {
        int lg = r >> 3, j = r & 7;
        _Float16 v = (r < 10) ? gh[r]
                   : (r < 20) ? gl[r-10]
                   : (r < 30) ? gh[r-20]
                   : (_Float16)0.f;
        dst[((size_t)lg*16 + c)*8 + j] = v;
    }
}

__global__ __launch_bounds__(256, 4) void gmf_main(
        const float* __restrict__ x,
        const half8* __restrict__ Bf,
        float* __restrict__ partial,   // [ksplit][N] (or out directly if ksplit==1)
        int N, int KT, int PTtot, int ksplit) {
    int tid  = threadIdx.x;
    int lane = tid & 63;
    int wid  = tid >> 6;
    int gwid = blockIdx.x * WPB + wid;
    int lg = lane >> 4;    // lane group
    int lr = lane & 15;    // A row / C col

    int split = blockIdx.y;
    int chunk = (KT + ksplit - 1) / ksplit;
    int kbeg = split * chunk;
    int kend = min(KT, kbeg + chunk);

    half8 afr[PT];
    f32x4 acc[PT];
    int   pts[PT];
    bool any_valid = false;

    #pragma unroll
    for (int t = 0; t < PT; ++t) {
        int pt = gwid * PT + t;
        pts[t] = pt;
        acc[t] = (f32x4){0.f, 0.f, 0.f, 0.f};
        if (pt < PTtot) any_valid = true;

        int n = pt * 16 + lr;
        float x0 = 0.f, x1 = 0.f, x2 = 0.f;
        if (pt < PTtot && n < N) { x0 = x[3*n]; x1 = x[3*n+1]; x2 = x[3*n+2]; }

        float P0 = x0*x0, P1 = x1*x1, P2 = x2*x2;
        float P3 = x0*x1, P4 = x0*x2, P5 = x1*x2;

        _Float16 h0 = (_Float16)P0, h1 = (_Float16)P1, h2 = (_Float16)P2;
        _Float16 h3 = (_Float16)P3, h4 = (_Float16)P4, h5 = (_Float16)P5;
        _Float16 h6 = (_Float16)x0, h7 = (_Float16)x1, h8 = (_Float16)x2;
        _Float16 h9 = (_Float16)1.f;
        _Float16 l0 = (_Float16)(P0 - (float)h0), l1 = (_Float16)(P1 - (float)h1);
        _Float16 l2 = (_Float16)(P2 - (float)h2), l3 = (_Float16)(P3 - (float)h3);
        _Float16 l4 = (_Float16)(P4 - (float)h4), l5 = (_Float16)(P5 - (float)h5);
        _Float16 l6 = (_Float16)(x0 - (float)h6), l7 = (_Float16)(x1 - (float)h7);
        _Float16 l8 = (_Float16)(x2 - (float)h8), l9 = (_Float16)0.f;
        _Float16 z  = (_Float16)0.f;

        half8 a;
        if      (lg == 0) a = (half8){h0,h1,h2,h3,h4,h5,h6,h7};
        else if (lg == 1) a = (half8){h8,h9,h0,h1,h2,h3,h4,h5};
        else if (lg == 2) a = (half8){h6,h7,h8,h9,l0,l1,l2,l3};
        else              a = (half8){l4,l5,l6,l7,l8,l9,z,z};
        afr[t] = a;
    }

    if (!any_valid) return;

    // Pinned zero quad: MFMA C operand, materialized once, never re-zeroed.
    float z0 = 0.f, z1 = 0.f, z2 = 0.f, z3 = 0.f;
    asm volatile("" : "+v"(z0), "+v"(z1), "+v"(z2), "+v"(z3));
    const f32x4 czero = {z0, z1, z2, z3};

    const f32x4 vscale = {EXP_SCALE, EXP_SCALE, EXP_SCALE, EXP_SCALE};
    const f32x4 vbias  = {EXP_BIAS,  EXP_BIAS,  EXP_BIAS,  EXP_BIAS};

#define GMF_BODY(BB)                                                             \
    {                                                                            \
        _Pragma("unroll")                                                        \
        for (int t = 0; t < PT; ++t) {                                           \
            f32x4 c = __builtin_amdgcn_mfma_f32_16x16x32_f16(                    \
                afr[t], (BB), czero, 0, 0, 0);                                   \
            f32x4 y = __builtin_elementwise_fma(c, vscale, vbias);               \
            acc[t].x += __uint_as_float(cvt_u32_sat(y.x));                       \
            acc[t].y += __uint_as_float(cvt_u32_sat(y.y));                       \
            acc[t].z += __uint_as_float(cvt_u32_sat(y.z));                       \
            acc[t].w += __uint_as_float(cvt_u32_sat(y.w));                       \
        }                                                                        \
    }

    if (kbeg < kend) {
        const half8* bp = Bf + lane;
        int nk = kend - kbeg;
        half8 b0 = bp[(size_t)kbeg * 64];
        half8 b1 = (nk > 1) ? bp[(size_t)(kbeg + 1) * 64] : b0;
        #pragma unroll 2
        for (int kt = kbeg; kt < kend - 2; ++kt) {
            half8 b = b0;
            b0 = b1;
            b1 = bp[(size_t)(kt + 2) * 64];   // 2-deep prefetch
            GMF_BODY(b)
        }
        if (nk > 1) GMF_BODY(b0)
        GMF_BODY(b1)
    }
#undef GMF_BODY

    float* dst_base = partial + (size_t)split * N;
    #pragma unroll
    for (int t = 0; t < PT; ++t) {
        f32x4 a = acc[t];
        #pragma unroll
        for (int m = 1; m <= 8; m <<= 1) {   // reduce over 16 cols
            a.x += __shfl_xor(a.x, m);
            a.y += __shfl_xor(a.y, m);
            a.z += __shfl_xor(a.z, m);
            a.w += __shfl_xor(a.w, m);
        }
        if (lr == 0 && pts[t] < PTtot) {
            int n0 = pts[t] * 16 + lg * 4;
            if (n0     < N) dst_base[n0]     = a.x;
            if (n0 + 1 < N) dst_base[n0 + 1] = a.y;
            if (n0 + 2 < N) dst_base[n0 + 2] = a.z;
            if (n0 + 3 < N) dst_base[n0 + 3] = a.w;
        }
    }
}

__global__ __launch_bounds__(256) void gmf_reduce(
        const float* __restrict__ partial,
        float* __restrict__ out, int N, int ksplit) {
    int j = blockIdx.x * blockDim.x + threadIdx.x;
    int n0 = 4 * j;
    if (n0 >= N) return;
    if (n0 + 3 < N) {
        float4 s = {0.f, 0.f, 0.f, 0.f};
        for (int sp = 0; sp < ksplit; ++sp) {
            float4 v = *(const float4*)(partial + (size_t)sp * N + n0);
            s.x += v.x; s.y += v.y; s.z += v.z; s.w += v.w;
        }
        *(float4*)(out + n0) = s;
    } else {
        for (int n = n0; n < N; ++n) {
            float s = 0.f;
            for (int sp = 0; sp < ksplit; ++sp) s += partial[(size_t)sp * N + n];
            out[n] = s;
        }
    }
}

extern "C" void kernel_launch(void* const* d_in, const int* in_sizes, int n_in,
                              void* d_out, int out_size, void* d_ws, size_t ws_size,
                              hipStream_t stream) {
    const float* x          = (const float*)d_in[0];
    const float* means      = (const float*)d_in[1];
    const float* log_scales = (const float*)d_in[2];
    const float* quats      = (const float*)d_in[3];
    const float* log_amps   = (const float*)d_in[4];
    float* out = (float*)d_out;

    int K = in_sizes[4];
    int N = out_size;
    int KT = (K + 15) / 16;
    int PTtot = (N + 15) / 16;

    size_t b_bytes = ((size_t)KT * 64 * 8 * sizeof(_Float16) + 255) & ~(size_t)255;
    _Float16* Bf = (_Float16*)d_ws;

    int ksplit = 1;
    for (int ks = KSPLIT; ks >= 2; ks >>= 1) {
        if (b_bytes + (size_t)ks * N * sizeof(float) <= ws_size) { ksplit = ks; break; }
    }
    bool use_partial = (ksplit > 1);

    gmf_precompute<<<(KT*16 + 255) / 256, 256, 0, stream>>>(
        means, log_scales, quats, log_amps, Bf, K, KT);

    int waves  = (PTtot + PT - 1) / PT;
    int blocks = (waves + WPB - 1) / WPB;

    if (use_partial) {
        float* partial = (float*)((char*)d_ws + b_bytes);
        dim3 grid(blocks, ksplit);
        gmf_main<<<grid, 256, 0, stream>>>(x, (const half8*)Bf, partial,
                                           N, KT, PTtot, ksplit);
        int nquads = (N + 3) / 4;
        gmf_reduce<<<(nquads + 255) / 256, 256, 0, stream>>>(partial, out, N, ksplit);
    } else {
        gmf_main<<<dim3(blocks, 1), 256, 0, stream>>>(x, (const half8*)Bf, out,
                                                      N, KT, PTtot, 1);
    }
}

// Round 11
// 49.652 us; speedup vs baseline: 1.0125x; 1.0125x over previous
//
#include <hip/hip_runtime.h>
#include <math.h>

// out[n] = sum_k exp2( t[n,k] ),  t[n,k] = sum_{j<10} P[n,j]*G[k,j]
// P = (x0^2,x1^2,x2^2, x0x1,x0x2,x1x2, x0,x1,x2, 1)
// G = h*(A00,A11,A22), 2h*(A01,A02,A12), L2E*(b0,b1,b2), h*c + log2(amp), h=-0.5*log2(e)
//
// MFMA f16 split-2 trick (one mfma_f32_16x16x32_f16 per 16x16 tile):
//   A cols [0..31] = [Phi(10) | Phi(10) | Plo(10) | 0 0]
//   B rows [0..31] = [Ghi(10) | Glo(10) | Ghi(10) | 0 0]
//
// exp2 via mean-zero Schraudolph (see prior rounds). KEY CHANGE vs round 10:
// empty-asm "+v" pins on the MFMA result and accumulators force the register
// allocator to keep the whole MFMA->fma->cvt->add chain in ARCH VGPRs.
// Theory: prior rounds' reported VGPR_Count 28-36 = arch VGPRs only; MFMA
// dest + acc lived in AGPRs, costing v_accvgpr_read/write pairs (~64 extra
// issue slots/iter = the persistent 2.4x VALU-busy bloat).

typedef _Float16 half8 __attribute__((ext_vector_type(8)));
typedef float    f32x4 __attribute__((ext_vector_type(4)));

#define PT     4    // point-tiles (16 points) per wave
#define WPB    4    // waves per block
#define KSPLIT 8    // gaussian-tile splits (blockIdx.y)

#define EXP_SCALE 8388608.0f        // 2^23
#define EXP_BIAS  1064880938.0f     // (127 - 0.0563) * 2^23, mean-zero bias

__device__ __forceinline__ unsigned cvt_u32_sat(float y) {
    unsigned u;
    asm("v_cvt_u32_f32 %0, %1" : "=v"(u) : "v"(y));   // saturates: y<0 -> 0
    return u;
}

__global__ __launch_bounds__(256) void gmf_precompute(
        const float* __restrict__ means,
        const float* __restrict__ log_scales,
        const float* __restrict__ quats,
        const float* __restrict__ log_amps,
        _Float16* __restrict__ Bf, int K, int KT) {
    int k = blockIdx.x * blockDim.x + threadIdx.x;
    if (k >= KT * 16) return;

    float gc[10];
    if (k < K) {
        float qw = quats[4*k+0], qx = quats[4*k+1], qy = quats[4*k+2], qz = quats[4*k+3];
        float qn = rsqrtf(qw*qw + qx*qx + qy*qy + qz*qz);
        qw *= qn; qx *= qn; qy *= qn; qz *= qn;

        float r00 = 1.f - 2.f*(qy*qy + qz*qz);
        float r01 = 2.f*(qx*qy - qw*qz);
        float r02 = 2.f*(qx*qz + qw*qy);
        float r10 = 2.f*(qx*qy + qw*qz);
        float r11 = 1.f - 2.f*(qx*qx + qz*qz);
        float r12 = 2.f*(qy*qz - qw*qx);
        float r20 = 2.f*(qx*qz - qw*qy);
        float r21 = 2.f*(qy*qz + qw*qx);
        float r22 = 1.f - 2.f*(qx*qx + qy*qy);

        float s0 = fminf(fmaxf(expf(log_scales[3*k+0]), 1e-5f), 100.f);
        float s1 = fminf(fmaxf(expf(log_scales[3*k+1]), 1e-5f), 100.f);
        float s2 = fminf(fmaxf(expf(log_scales[3*k+2]), 1e-5f), 100.f);
        float v0 = s0*s0, v1 = s1*s1, v2 = s2*s2;

        float S00 = r00*r00*v0 + r01*r01*v1 + r02*r02*v2 + 1e-5f;
        float S11 = r10*r10*v0 + r11*r11*v1 + r12*r12*v2 + 1e-5f;
        float S22 = r20*r20*v0 + r21*r21*v1 + r22*r22*v2 + 1e-5f;
        float S01 = r00*r10*v0 + r01*r11*v1 + r02*r12*v2;
        float S02 = r00*r20*v0 + r01*r21*v1 + r02*r22*v2;
        float S12 = r10*r20*v0 + r11*r21*v1 + r12*r22*v2;

        float c00 = S11*S22 - S12*S12;
        float c01 = S02*S12 - S01*S22;
        float c02 = S01*S12 - S02*S11;
        float det = S00*c00 + S01*c01 + S02*c02;
        float id  = 1.f/det;
        float A00 = c00*id, A01 = c01*id, A02 = c02*id;
        float A11 = (S00*S22 - S02*S02)*id;
        float A12 = (S01*S02 - S00*S12)*id;
        float A22 = (S00*S11 - S01*S01)*id;

        float m0 = means[3*k+0], m1 = means[3*k+1], m2 = means[3*k+2];
        float b0 = A00*m0 + A01*m1 + A02*m2;
        float b1 = A01*m0 + A11*m1 + A12*m2;
        float b2 = A02*m0 + A12*m1 + A22*m2;
        float cc = b0*m0 + b1*m1 + b2*m2;

        float la = fminf(fmaxf(log_amps[k], -10.f), 6.f);
        const float L2E = 1.4426950408889634f;
        const float h = -0.5f * L2E;

        gc[0] = h*A00; gc[1] = h*A11; gc[2] = h*A22;
        gc[3] = 2.f*h*A01; gc[4] = 2.f*h*A02; gc[5] = 2.f*h*A12;
        gc[6] = L2E*b0; gc[7] = L2E*b1; gc[8] = L2E*b2;
        gc[9] = h*cc + L2E*la;
    } else {
        #pragma unroll
        for (int j = 0; j < 10; ++j) gc[j] = 0.f;
        gc[9] = -60000.f;   // pad gaussian -> saturates to 0 in fast exp2
    }

    _Float16 gh[10], gl[10];
    #pragma unroll
    for (int j = 0; j < 10; ++j) {
        gh[j] = (_Float16)gc[j];
        gl[j] = (_Float16)(gc[j] - (float)gh[j]);
    }

    int kt = k >> 4, c = k & 15;
    _Float16* dst = Bf + (size_t)kt * 64 * 8;
    #pragma unroll 32
    for (int r = 0; r < 32; ++r) {
        int lg = r >> 3, j = r & 7;
        _Float16 v = (r < 10) ? gh[r]
                   : (r < 20) ? gl[r-10]
                   : (r < 30) ? gh[r-20]
                   : (_Float16)0.f;
        dst[((size_t)lg*16 + c)*8 + j] = v;
    }
}

__global__ __launch_bounds__(256, 4) void gmf_main(
        const float* __restrict__ x,
        const half8* __restrict__ Bf,
        float* __restrict__ partial,   // [ksplit][N] (or out directly if ksplit==1)
        int N, int KT, int PTtot, int ksplit) {
    int tid  = threadIdx.x;
    int lane = tid & 63;
    int wid  = tid >> 6;
    int gwid = blockIdx.x * WPB + wid;
    int lg = lane >> 4;    // lane group
    int lr = lane & 15;    // A row / C col

    int split = blockIdx.y;
    int chunk = (KT + ksplit - 1) / ksplit;
    int kbeg = split * chunk;
    int kend = min(KT, kbeg + chunk);

    half8 afr[PT];
    f32x4 acc[PT];
    int   pts[PT];
    bool any_valid = false;

    #pragma unroll
    for (int t = 0; t < PT; ++t) {
        int pt = gwid * PT + t;
        pts[t] = pt;
        acc[t] = (f32x4){0.f, 0.f, 0.f, 0.f};
        if (pt < PTtot) any_valid = true;

        int n = pt * 16 + lr;
        float x0 = 0.f, x1 = 0.f, x2 = 0.f;
        if (pt < PTtot && n < N) { x0 = x[3*n]; x1 = x[3*n+1]; x2 = x[3*n+2]; }

        float P0 = x0*x0, P1 = x1*x1, P2 = x2*x2;
        float P3 = x0*x1, P4 = x0*x2, P5 = x1*x2;

        _Float16 h0 = (_Float16)P0, h1 = (_Float16)P1, h2 = (_Float16)P2;
        _Float16 h3 = (_Float16)P3, h4 = (_Float16)P4, h5 = (_Float16)P5;
        _Float16 h6 = (_Float16)x0, h7 = (_Float16)x1, h8 = (_Float16)x2;
        _Float16 h9 = (_Float16)1.f;
        _Float16 l0 = (_Float16)(P0 - (float)h0), l1 = (_Float16)(P1 - (float)h1);
        _Float16 l2 = (_Float16)(P2 - (float)h2), l3 = (_Float16)(P3 - (float)h3);
        _Float16 l4 = (_Float16)(P4 - (float)h4), l5 = (_Float16)(P5 - (float)h5);
        _Float16 l6 = (_Float16)(x0 - (float)h6), l7 = (_Float16)(x1 - (float)h7);
        _Float16 l8 = (_Float16)(x2 - (float)h8), l9 = (_Float16)0.f;
        _Float16 z  = (_Float16)0.f;

        half8 a;
        if      (lg == 0) a = (half8){h0,h1,h2,h3,h4,h5,h6,h7};
        else if (lg == 1) a = (half8){h8,h9,h0,h1,h2,h3,h4,h5};
        else if (lg == 2) a = (half8){h6,h7,h8,h9,l0,l1,l2,l3};
        else              a = (half8){l4,l5,l6,l7,l8,l9,z,z};
        afr[t] = a;
    }

    if (!any_valid) return;

    // Pinned zero quad: MFMA C operand, materialized once in VGPRs.
    float z0 = 0.f, z1 = 0.f, z2 = 0.f, z3 = 0.f;
    asm volatile("" : "+v"(z0), "+v"(z1), "+v"(z2), "+v"(z3));
    const f32x4 czero = {z0, z1, z2, z3};

    const f32x4 vscale = {EXP_SCALE, EXP_SCALE, EXP_SCALE, EXP_SCALE};
    const f32x4 vbias  = {EXP_BIAS,  EXP_BIAS,  EXP_BIAS,  EXP_BIAS};

    // Pin accumulators into arch VGPRs before the loop.
    #pragma unroll
    for (int t = 0; t < PT; ++t) asm volatile("" : "+v"(acc[t]));

#define GMF_BODY(BB)                                                             \
    {                                                                            \
        _Pragma("unroll")                                                        \
        for (int t = 0; t < PT; ++t) {                                           \
            f32x4 c = __builtin_amdgcn_mfma_f32_16x16x32_f16(                    \
                afr[t], (BB), czero, 0, 0, 0);                                   \
            asm volatile("" : "+v"(c));          /* force MFMA D into VGPRs */   \
            f32x4 y = __builtin_elementwise_fma(c, vscale, vbias);               \
            acc[t].x += __uint_as_float(cvt_u32_sat(y.x));                       \
            acc[t].y += __uint_as_float(cvt_u32_sat(y.y));                       \
            acc[t].z += __uint_as_float(cvt_u32_sat(y.z));                       \
            acc[t].w += __uint_as_float(cvt_u32_sat(y.w));                       \
            asm volatile("" : "+v"(acc[t]));     /* keep acc in VGPRs */         \
        }                                                                        \
    }

    if (kbeg < kend) {
        const half8* bp = Bf + lane;
        int nk = kend - kbeg;
        half8 b0 = bp[(size_t)kbeg * 64];
        half8 b1 = (nk > 1) ? bp[(size_t)(kbeg + 1) * 64] : b0;
        #pragma unroll 2
        for (int kt = kbeg; kt < kend - 2; ++kt) {
            half8 b = b0;
            b0 = b1;
            b1 = bp[(size_t)(kt + 2) * 64];   // 2-deep prefetch
            GMF_BODY(b)
        }
        if (nk > 1) GMF_BODY(b0)
        GMF_BODY(b1)
    }
#undef GMF_BODY

    float* dst_base = partial + (size_t)split * N;
    #pragma unroll
    for (int t = 0; t < PT; ++t) {
        f32x4 a = acc[t];
        #pragma unroll
        for (int m = 1; m <= 8; m <<= 1) {   // reduce over 16 cols
            a.x += __shfl_xor(a.x, m);
            a.y += __shfl_xor(a.y, m);
            a.z += __shfl_xor(a.z, m);
            a.w += __shfl_xor(a.w, m);
        }
        if (lr == 0 && pts[t] < PTtot) {
            int n0 = pts[t] * 16 + lg * 4;
            if (n0     < N) dst_base[n0]     = a.x;
            if (n0 + 1 < N) dst_base[n0 + 1] = a.y;
            if (n0 + 2 < N) dst_base[n0 + 2] = a.z;
            if (n0 + 3 < N) dst_base[n0 + 3] = a.w;
        }
    }
}

__global__ __launch_bounds__(256) void gmf_reduce(
        const float* __restrict__ partial,
        float* __restrict__ out, int N, int ksplit) {
    int j = blockIdx.x * blockDim.x + threadIdx.x;
    int n0 = 4 * j;
    if (n0 >= N) return;
    if (n0 + 3 < N) {
        float4 s = {0.f, 0.f, 0.f, 0.f};
        for (int sp = 0; sp < ksplit; ++sp) {
            float4 v = *(const float4*)(partial + (size_t)sp * N + n0);
            s.x += v.x; s.y += v.y; s.z += v.z; s.w += v.w;
        }
        *(float4*)(out + n0) = s;
    } else {
        for (int n = n0; n < N; ++n) {
            float s = 0.f;
            for (int sp = 0; sp < ksplit; ++sp) s += partial[(size_t)sp * N + n];
            out[n] = s;
        }
    }
}

extern "C" void kernel_launch(void* const* d_in, const int* in_sizes, int n_in,
                              void* d_out, int out_size, void* d_ws, size_t ws_size,
                              hipStream_t stream) {
    const float* x          = (const float*)d_in[0];
    const float* means      = (const float*)d_in[1];
    const float* log_scales = (const float*)d_in[2];
    const float* quats      = (const float*)d_in[3];
    const float* log_amps   = (const float*)d_in[4];
    float* out = (float*)d_out;

    int K = in_sizes[4];
    int N = out_size;
    int KT = (K + 15) / 16;
    int PTtot = (N + 15) / 16;

    size_t b_bytes = ((size_t)KT * 64 * 8 * sizeof(_Float16) + 255) & ~(size_t)255;
    _Float16* Bf = (_Float16*)d_ws;

    int ksplit = 1;
    for (int ks = KSPLIT; ks >= 2; ks >>= 1) {
        if (b_bytes + (size_t)ks * N * sizeof(float) <= ws_size) { ksplit = ks; break; }
    }
    bool use_partial = (ksplit > 1);

    gmf_precompute<<<(KT*16 + 255) / 256, 256, 0, stream>>>(
        means, log_scales, quats, log_amps, Bf, K, KT);

    int waves  = (PTtot + PT - 1) / PT;
    int blocks = (waves + WPB - 1) / WPB;

    if (use_partial) {
        float* partial = (float*)((char*)d_ws + b_bytes);
        dim3 grid(blocks, ksplit);
        gmf_main<<<grid, 256, 0, stream>>>(x, (const half8*)Bf, partial,
                                           N, KT, PTtot, ksplit);
        int nquads = (N + 3) / 4;
        gmf_reduce<<<(nquads + 255) / 256, 256, 0, stream>>>(partial, out, N, ksplit);
    } else {
        gmf_main<<<dim3(blocks, 1), 256, 0, stream>>>(x, (const half8*)Bf, out,
                                                      N, KT, PTtot, 1);
    }
}

// Round 12
// 47.363 us; speedup vs baseline: 1.0615x; 1.0483x over previous
//
#include <hip/hip_runtime.h>
#include <math.h>

// out[n] = sum_k exp2( t[n,k] ),  t[n,k] = sum_{j<10} P[n,j]*G[k,j]
// P = (x0^2,x1^2,x2^2, x0x1,x0x2,x1x2, x0,x1,x2, 1)
// G = h*(A00,A11,A22), 2h*(A01,A02,A12), L2E*(b0,b1,b2), h*c + log2(amp), h=-0.5*log2(e)
//
// MFMA f16 split-2 trick (one mfma_f32_16x16x32_f16 per 16x16 tile):
//   A cols [0..31] = [Phi(10) | Phi(10) | Plo(10) | 0 0]
//   B rows [0..31] = [Ghi(10) | Glo(10) | Ghi(10) | 0 0]
//
// exp2 via mean-zero Schraudolph: y=fma(t,2^23,B); v_cvt_u32_f32 saturates
// y<0 -> 0 (incl. -60000 pad gaussians); acc += bitcast(u). Ripple +-3.8%
// mean-zero.
//
// ROUND 12 KEY CHANGE: two-stage software pipeline. Iteration i's exp/acc
// VALU work executes under the shadow of iteration i+1's MFMA issue+latency
// (named cP/cQ sets, unroll-by-2, no runtime-indexed rotation). 3-deep
// unguarded B prefetch (Bf padded +2 tiles). Theory: rounds 4-11 were
// latency-stalled (per-SIMD VALU issue only ~23%; VALUBusy is CU-level).

typedef _Float16 half8 __attribute__((ext_vector_type(8)));
typedef float    f32x4 __attribute__((ext_vector_type(4)));
typedef float    v2f   __attribute__((ext_vector_type(2)));

#define PT     4    // point-tiles (16 points) per wave
#define WPB    4    // waves per block
#define KSPLIT 8    // gaussian-tile splits (blockIdx.y)

#define EXP_SCALE 8388608.0f        // 2^23
#define EXP_BIAS  1064880938.0f     // (127 - 0.0563) * 2^23, mean-zero bias

__device__ __forceinline__ unsigned cvt_u32_sat(float y) {
    unsigned u;
    asm("v_cvt_u32_f32 %0, %1" : "=v"(u) : "v"(y));   // saturates: y<0 -> 0
    return u;
}

__global__ __launch_bounds__(256) void gmf_precompute(
        const float* __restrict__ means,
        const float* __restrict__ log_scales,
        const float* __restrict__ quats,
        const float* __restrict__ log_amps,
        _Float16* __restrict__ Bf, int K, int KT) {
    int k = blockIdx.x * blockDim.x + threadIdx.x;
    if (k >= KT * 16) return;

    float gc[10];
    if (k < K) {
        float qw = quats[4*k+0], qx = quats[4*k+1], qy = quats[4*k+2], qz = quats[4*k+3];
        float qn = rsqrtf(qw*qw + qx*qx + qy*qy + qz*qz);
        qw *= qn; qx *= qn; qy *= qn; qz *= qn;

        float r00 = 1.f - 2.f*(qy*qy + qz*qz);
        float r01 = 2.f*(qx*qy - qw*qz);
        float r02 = 2.f*(qx*qz + qw*qy);
        float r10 = 2.f*(qx*qy + qw*qz);
        float r11 = 1.f - 2.f*(qx*qx + qz*qz);
        float r12 = 2.f*(qy*qz - qw*qx);
        float r20 = 2.f*(qx*qz - qw*qy);
        float r21 = 2.f*(qy*qz + qw*qx);
        float r22 = 1.f - 2.f*(qx*qx + qy*qy);

        float s0 = fminf(fmaxf(expf(log_scales[3*k+0]), 1e-5f), 100.f);
        float s1 = fminf(fmaxf(expf(log_scales[3*k+1]), 1e-5f), 100.f);
        float s2 = fminf(fmaxf(expf(log_scales[3*k+2]), 1e-5f), 100.f);
        float v0 = s0*s0, v1 = s1*s1, v2 = s2*s2;

        float S00 = r00*r00*v0 + r01*r01*v1 + r02*r02*v2 + 1e-5f;
        float S11 = r10*r10*v0 + r11*r11*v1 + r12*r12*v2 + 1e-5f;
        float S22 = r20*r20*v0 + r21*r21*v1 + r22*r22*v2 + 1e-5f;
        float S01 = r00*r10*v0 + r01*r11*v1 + r02*r12*v2;
        float S02 = r00*r20*v0 + r01*r21*v1 + r02*r22*v2;
        float S12 = r10*r20*v0 + r11*r21*v1 + r12*r22*v2;

        float c00 = S11*S22 - S12*S12;
        float c01 = S02*S12 - S01*S22;
        float c02 = S01*S12 - S02*S11;
        float det = S00*c00 + S01*c01 + S02*c02;
        float id  = 1.f/det;
        float A00 = c00*id, A01 = c01*id, A02 = c02*id;
        float A11 = (S00*S22 - S02*S02)*id;
        float A12 = (S01*S02 - S00*S12)*id;
        float A22 = (S00*S11 - S01*S01)*id;

        float m0 = means[3*k+0], m1 = means[3*k+1], m2 = means[3*k+2];
        float b0 = A00*m0 + A01*m1 + A02*m2;
        float b1 = A01*m0 + A11*m1 + A12*m2;
        float b2 = A02*m0 + A12*m1 + A22*m2;
        float cc = b0*m0 + b1*m1 + b2*m2;

        float la = fminf(fmaxf(log_amps[k], -10.f), 6.f);
        const float L2E = 1.4426950408889634f;
        const float h = -0.5f * L2E;

        gc[0] = h*A00; gc[1] = h*A11; gc[2] = h*A22;
        gc[3] = 2.f*h*A01; gc[4] = 2.f*h*A02; gc[5] = 2.f*h*A12;
        gc[6] = L2E*b0; gc[7] = L2E*b1; gc[8] = L2E*b2;
        gc[9] = h*cc + L2E*la;
    } else {
        #pragma unroll
        for (int j = 0; j < 10; ++j) gc[j] = 0.f;
        gc[9] = -60000.f;   // pad gaussian -> saturates to 0 in fast exp2
    }

    _Float16 gh[10], gl[10];
    #pragma unroll
    for (int j = 0; j < 10; ++j) {
        gh[j] = (_Float16)gc[j];
        gl[j] = (_Float16)(gc[j] - (float)gh[j]);
    }

    int kt = k >> 4, c = k & 15;
    _Float16* dst = Bf + (size_t)kt * 64 * 8;
    #pragma unroll 32
    for (int r = 0; r < 32; ++r) {
        int lg = r >> 3, j = r & 7;
        _Float16 v = (r < 10) ? gh[r]
                   : (r < 20) ? gl[r-10]
                   : (r < 30) ? gh[r-20]
                   : (_Float16)0.f;
        dst[((size_t)lg*16 + c)*8 + j] = v;
    }
}

__global__ __launch_bounds__(256, 2) void gmf_main(
        const float* __restrict__ x,
        const half8* __restrict__ Bf,
        float* __restrict__ partial,   // [ksplit][N] (or out directly if ksplit==1)
        int N, int KT, int PTtot, int ksplit) {
    int tid  = threadIdx.x;
    int lane = tid & 63;
    int wid  = tid >> 6;
    int gwid = blockIdx.x * WPB + wid;
    int lg = lane >> 4;    // lane group
    int lr = lane & 15;    // A row / C col

    int split = blockIdx.y;
    int chunk = (KT + ksplit - 1) / ksplit;
    int kbeg = split * chunk;
    int kend = min(KT, kbeg + chunk);

    half8 afr[PT];
    v2f   acc01[PT], acc23[PT];
    int   pts[PT];
    bool any_valid = false;

    #pragma unroll
    for (int t = 0; t < PT; ++t) {
        int pt = gwid * PT + t;
        pts[t] = pt;
        acc01[t] = (v2f){0.f, 0.f};
        acc23[t] = (v2f){0.f, 0.f};
        if (pt < PTtot) any_valid = true;

        int n = pt * 16 + lr;
        float x0 = 0.f, x1 = 0.f, x2 = 0.f;
        if (pt < PTtot && n < N) { x0 = x[3*n]; x1 = x[3*n+1]; x2 = x[3*n+2]; }

        float P0 = x0*x0, P1 = x1*x1, P2 = x2*x2;
        float P3 = x0*x1, P4 = x0*x2, P5 = x1*x2;

        _Float16 h0 = (_Float16)P0, h1 = (_Float16)P1, h2 = (_Float16)P2;
        _Float16 h3 = (_Float16)P3, h4 = (_Float16)P4, h5 = (_Float16)P5;
        _Float16 h6 = (_Float16)x0, h7 = (_Float16)x1, h8 = (_Float16)x2;
        _Float16 h9 = (_Float16)1.f;
        _Float16 l0 = (_Float16)(P0 - (float)h0), l1 = (_Float16)(P1 - (float)h1);
        _Float16 l2 = (_Float16)(P2 - (float)h2), l3 = (_Float16)(P3 - (float)h3);
        _Float16 l4 = (_Float16)(P4 - (float)h4), l5 = (_Float16)(P5 - (float)h5);
        _Float16 l6 = (_Float16)(x0 - (float)h6), l7 = (_Float16)(x1 - (float)h7);
        _Float16 l8 = (_Float16)(x2 - (float)h8), l9 = (_Float16)0.f;
        _Float16 z  = (_Float16)0.f;

        half8 a;
        if      (lg == 0) a = (half8){h0,h1,h2,h3,h4,h5,h6,h7};
        else if (lg == 1) a = (half8){h8,h9,h0,h1,h2,h3,h4,h5};
        else if (lg == 2) a = (half8){h6,h7,h8,h9,l0,l1,l2,l3};
        else              a = (half8){l4,l5,l6,l7,l8,l9,z,z};
        afr[t] = a;
    }

    if (!any_valid) return;

    // Pinned zero quad: MFMA C operand, materialized once.
    float z0 = 0.f, z1 = 0.f, z2 = 0.f, z3 = 0.f;
    asm volatile("" : "+v"(z0), "+v"(z1), "+v"(z2), "+v"(z3));
    const f32x4 czero = {z0, z1, z2, z3};

    const f32x4 vscale = {EXP_SCALE, EXP_SCALE, EXP_SCALE, EXP_SCALE};
    const f32x4 vbias  = {EXP_BIAS,  EXP_BIAS,  EXP_BIAS,  EXP_BIAS};

#define EXPACC(CC)                                                              \
    { _Pragma("unroll")                                                         \
      for (int t = 0; t < PT; ++t) {                                            \
          f32x4 y = __builtin_elementwise_fma((CC)[t], vscale, vbias);          \
          v2f e01 = {__uint_as_float(cvt_u32_sat(y.x)),                         \
                     __uint_as_float(cvt_u32_sat(y.y))};                        \
          v2f e23 = {__uint_as_float(cvt_u32_sat(y.z)),                         \
                     __uint_as_float(cvt_u32_sat(y.w))};                        \
          acc01[t] += e01;                                                      \
          acc23[t] += e23;                                                      \
      } }

#define MFMA4(DST, BB)                                                          \
    { _Pragma("unroll")                                                         \
      for (int t = 0; t < PT; ++t)                                              \
          (DST)[t] = __builtin_amdgcn_mfma_f32_16x16x32_f16(                    \
              afr[t], (BB), czero, 0, 0, 0); }

    if (kbeg < kend) {
        const half8* bp = Bf + lane;
        // Bf is padded +2 tiles, so all prefetch indices below are in-bounds.
        half8 bc = bp[(size_t)kbeg * 64];
        half8 p1 = bp[(size_t)(kbeg + 1) * 64];
        half8 p2 = bp[(size_t)(kbeg + 2) * 64];

        f32x4 cP[PT], cQ[PT];
        MFMA4(cP, bc)

        int kt = kbeg + 1;
        for (; kt + 1 < kend; kt += 2) {
            half8 bA = p1;
            half8 bB = p2;
            p1 = bp[(size_t)(kt + 2) * 64];
            p2 = bp[(size_t)(kt + 3) * 64];
            MFMA4(cQ, bA)     // issue next MFMAs...
            EXPACC(cP)        // ...then do previous exp/acc under their shadow
            MFMA4(cP, bB)
            EXPACC(cQ)
        }
        if (kt < kend) {      // odd tail
            half8 bA = p1;
            MFMA4(cQ, bA)
            EXPACC(cP)
            EXPACC(cQ)
        } else {
            EXPACC(cP)
        }
    }
#undef MFMA4
#undef EXPACC

    float* dst_base = partial + (size_t)split * N;
    #pragma unroll
    for (int t = 0; t < PT; ++t) {
        f32x4 a = {acc01[t].x, acc01[t].y, acc23[t].x, acc23[t].y};
        #pragma unroll
        for (int m = 1; m <= 8; m <<= 1) {   // reduce over 16 cols
            a.x += __shfl_xor(a.x, m);
            a.y += __shfl_xor(a.y, m);
            a.z += __shfl_xor(a.z, m);
            a.w += __shfl_xor(a.w, m);
        }
        if (lr == 0 && pts[t] < PTtot) {
            int n0 = pts[t] * 16 + lg * 4;
            if (n0     < N) dst_base[n0]     = a.x;
            if (n0 + 1 < N) dst_base[n0 + 1] = a.y;
            if (n0 + 2 < N) dst_base[n0 + 2] = a.z;
            if (n0 + 3 < N) dst_base[n0 + 3] = a.w;
        }
    }
}

__global__ __launch_bounds__(256) void gmf_reduce(
        const float* __restrict__ partial,
        float* __restrict__ out, int N, int ksplit) {
    int j = blockIdx.x * blockDim.x + threadIdx.x;
    int n0 = 4 * j;
    if (n0 >= N) return;
    if (n0 + 3 < N) {
        float4 s = {0.f, 0.f, 0.f, 0.f};
        for (int sp = 0; sp < ksplit; ++sp) {
            float4 v = *(const float4*)(partial + (size_t)sp * N + n0);
            s.x += v.x; s.y += v.y; s.z += v.z; s.w += v.w;
        }
        *(float4*)(out + n0) = s;
    } else {
        for (int n = n0; n < N; ++n) {
            float s = 0.f;
            for (int sp = 0; sp < ksplit; ++sp) s += partial[(size_t)sp * N + n];
            out[n] = s;
        }
    }
}

extern "C" void kernel_launch(void* const* d_in, const int* in_sizes, int n_in,
                              void* d_out, int out_size, void* d_ws, size_t ws_size,
                              hipStream_t stream) {
    const float* x          = (const float*)d_in[0];
    const float* means      = (const float*)d_in[1];
    const float* log_scales = (const float*)d_in[2];
    const float* quats      = (const float*)d_in[3];
    const float* log_amps   = (const float*)d_in[4];
    float* out = (float*)d_out;

    int K = in_sizes[4];
    int N = out_size;
    int KT = (K + 15) / 16;
    int PTtot = (N + 15) / 16;

    // +2 tiles of padding so the pipeline's unguarded prefetch stays in-bounds.
    size_t b_bytes = (((size_t)(KT + 2)) * 64 * 8 * sizeof(_Float16) + 255) & ~(size_t)255;
    _Float16* Bf = (_Float16*)d_ws;

    int ksplit = 1;
    for (int ks = KSPLIT; ks >= 2; ks >>= 1) {
        if (b_bytes + (size_t)ks * N * sizeof(float) <= ws_size) { ksplit = ks; break; }
    }
    bool use_partial = (ksplit > 1);

    gmf_precompute<<<(KT*16 + 255) / 256, 256, 0, stream>>>(
        means, log_scales, quats, log_amps, Bf, K, KT);

    int waves  = (PTtot + PT - 1) / PT;
    int blocks = (waves + WPB - 1) / WPB;

    if (use_partial) {
        float* partial = (float*)((char*)d_ws + b_bytes);
        dim3 grid(blocks, ksplit);
        gmf_main<<<grid, 256, 0, stream>>>(x, (const half8*)Bf, partial,
                                           N, KT, PTtot, ksplit);
        int nquads = (N + 3) / 4;
        gmf_reduce<<<(nquads + 255) / 256, 256, 0, stream>>>(partial, out, N, ksplit);
    } else {
        gmf_main<<<dim3(blocks, 1), 256, 0, stream>>>(x, (const half8*)Bf, out,
                                                      N, KT, PTtot, 1);
    }
}